// Round 2
// baseline (129.790 us; speedup 1.0000x reference)
//
#include <hip/hip_runtime.h>

#define K_CW 256

// Precompute c_sq[k] with numpy rounding: ((c0*c0 + c1*c1) + c2*c2) + c3*c3
// (separate multiply temp then pairwise-sum n=4 sequential -> adds of rounded squares)
__global__ void vq_csq_kernel(const float* __restrict__ tlut, float* __restrict__ csq) {
    int k = threadIdx.x;  // launched with 256 threads, 1 block
    float c0 = tlut[k * 4 + 0];
    float c1 = tlut[k * 4 + 1];
    float c2 = tlut[k * 4 + 2];
    float c3 = tlut[k * 4 + 3];
    float s = __fadd_rn(__fadd_rn(__fadd_rn(__fmul_rn(c0, c0), __fmul_rn(c1, c1)),
                                  __fmul_rn(c2, c2)),
                        __fmul_rn(c3, c3));
    csq[k] = s;
}

__device__ __forceinline__ float dist2_ref(float x0, float x1, float x2, float x3,
                                           float xsq, float4 c, float cs) {
    // cross: numpy einsum inner loop is `accum += a*b` compiled with fp-contract
    // -> sequential FMA chain ascending over d (first product plain-rounded,
    //    identical to fma(a,b,0)).
    float cross = __fmul_rn(x0, c.x);
    cross = __fmaf_rn(x1, c.y, cross);
    cross = __fmaf_rn(x2, c.z, cross);
    cross = __fmaf_rn(x3, c.w, cross);
    // dist2 = (x_sq - 2*cross) + c_sq ; 2*cross is exact so
    // fma(-2, cross, xsq) == rn(xsq - rn(2*cross)) bit-exactly.
    float t = __fmaf_rn(-2.0f, cross, xsq);
    return __fadd_rn(t, cs);
}

__global__ __launch_bounds__(256) void vq_argmin_kernel(
    const float* __restrict__ X,
    const float* __restrict__ tlut,
    const float* __restrict__ csq,
    float* __restrict__ outX,   // [B,4] reconstruction
    float* __restrict__ outS,   // [B] state, stored as float (harness reads f32)
    int B) {
    int p = blockIdx.x * blockDim.x + threadIdx.x;
    if (p >= B) return;

    const float4 xv = reinterpret_cast<const float4*>(X)[p];
    const float x0 = xv.x, x1 = xv.y, x2 = xv.z, x3 = xv.w;

    // x_sq with numpy's rounding: sequential adds of rounded squares
    float xsq = __fadd_rn(__fadd_rn(__fadd_rn(__fmul_rn(x0, x0), __fmul_rn(x1, x1)),
                                    __fmul_rn(x2, x2)),
                          __fmul_rn(x3, x3));

    float bestd = __builtin_inff();
    int besti = 0;

    // two independent distance chains per iteration for ILP
    #pragma unroll 4
    for (int k = 0; k < K_CW; k += 2) {
        const float4 ca = reinterpret_cast<const float4*>(tlut)[k];      // wave-uniform -> s_load
        const float4 cb = reinterpret_cast<const float4*>(tlut)[k + 1];
        float da = dist2_ref(x0, x1, x2, x3, xsq, ca, csq[k]);
        float db = dist2_ref(x0, x1, x2, x3, xsq, cb, csq[k + 1]);
        // strict '<' keeps FIRST occurrence of the minimum (np.argmin semantics),
        // checked in ascending k order.
        if (da < bestd) { bestd = da; besti = k; }
        if (db < bestd) { bestd = db; besti = k + 1; }
    }

    const float4 cw = reinterpret_cast<const float4*>(tlut)[besti];
    reinterpret_cast<float4*>(outX)[p] = cw;
    outS[p] = (float)besti;
}

extern "C" void kernel_launch(void* const* d_in, const int* in_sizes, int n_in,
                              void* d_out, int out_size, void* d_ws, size_t ws_size,
                              hipStream_t stream) {
    const float* X    = (const float*)d_in[0];   // [B,4]
    const float* tlut = (const float*)d_in[1];   // [256,4]
    const int B = in_sizes[0] / 4;

    float* outX = (float*)d_out;          // first B*4 floats: hatX
    float* outS = outX + (size_t)B * 4;   // next B floats: state (as float)

    float* csq = (float*)d_ws;            // 256 floats of scratch

    vq_csq_kernel<<<1, 256, 0, stream>>>(tlut, csq);

    const int block = 256;
    const int grid = (B + block - 1) / block;
    vq_argmin_kernel<<<grid, block, 0, stream>>>(X, tlut, csq, outX, outS, B);
}

// Round 3
// 119.839 us; speedup vs baseline: 1.0830x; 1.0830x over previous
//
#include <hip/hip_runtime.h>

#define K_CW 256
#define PPT 4  // points per thread

// Precompute c_sq[k] with numpy rounding: ((c0*c0 + c1*c1) + c2*c2) + c3*c3
__global__ void vq_csq_kernel(const float* __restrict__ tlut, float* __restrict__ csq) {
    int k = threadIdx.x;  // launched with 256 threads, 1 block
    float c0 = tlut[k * 4 + 0];
    float c1 = tlut[k * 4 + 1];
    float c2 = tlut[k * 4 + 2];
    float c3 = tlut[k * 4 + 3];
    float s = __fadd_rn(__fadd_rn(__fadd_rn(__fmul_rn(c0, c0), __fmul_rn(c1, c1)),
                                  __fmul_rn(c2, c2)),
                        __fmul_rn(c3, c3));
    csq[k] = s;
}

__global__ __launch_bounds__(256) void vq_argmin_kernel(
    const float* __restrict__ X,
    const float* __restrict__ tlut,
    const float* __restrict__ csq,
    float* __restrict__ outX,   // [B,4] reconstruction
    float* __restrict__ outS,   // [B] state, stored as float
    int B) {
    const int tid = blockIdx.x * blockDim.x + threadIdx.x;
    const int stride = B / PPT;       // strided point assignment -> coalesced per instr
    if (tid >= stride) return;

    const float4* __restrict__ X4 = reinterpret_cast<const float4*>(X);
    const float4* __restrict__ T4 = reinterpret_cast<const float4*>(tlut);

    float x0[PPT], x1[PPT], x2[PPT], x3[PPT], xsq[PPT], bestd[PPT];
    int besti[PPT];

    #pragma unroll
    for (int i = 0; i < PPT; ++i) {
        const float4 xv = X4[tid + i * stride];
        x0[i] = xv.x; x1[i] = xv.y; x2[i] = xv.z; x3[i] = xv.w;
        // x_sq with numpy rounding: sequential adds of rounded squares
        xsq[i] = __fadd_rn(__fadd_rn(__fadd_rn(__fmul_rn(xv.x, xv.x), __fmul_rn(xv.y, xv.y)),
                                     __fmul_rn(xv.z, xv.z)),
                           __fmul_rn(xv.w, xv.w));
        bestd[i] = __builtin_inff();
        besti[i] = 0;
    }

    #pragma unroll 4
    for (int k = 0; k < K_CW; ++k) {
        const float4 c = T4[k];       // wave-uniform -> s_load_dwordx4 (scalar pipe)
        const float cs = csq[k];      // wave-uniform -> s_load_dword
        #pragma unroll
        for (int i = 0; i < PPT; ++i) {
            // cross: numpy einsum `accum += a*b` with fp-contract -> ascending FMA chain
            float cross = __fmul_rn(x0[i], c.x);
            cross = __fmaf_rn(x1[i], c.y, cross);
            cross = __fmaf_rn(x2[i], c.z, cross);
            cross = __fmaf_rn(x3[i], c.w, cross);
            // (x_sq - 2*cross) + c_sq ; fma(-2,cross,xsq) == rn(xsq - rn(2*cross)) exactly
            float t = __fmaf_rn(-2.0f, cross, xsq[i]);
            float d = __fadd_rn(t, cs);
            // strict '<' keeps FIRST occurrence (np.argmin), ascending k
            bool lt = d < bestd[i];
            besti[i] = lt ? k : besti[i];
            bestd[i] = lt ? d : bestd[i];
        }
    }

    #pragma unroll
    for (int i = 0; i < PPT; ++i) {
        const int p = tid + i * stride;
        reinterpret_cast<float4*>(outX)[p] = T4[besti[i]];
        outS[p] = (float)besti[i];
    }
}

extern "C" void kernel_launch(void* const* d_in, const int* in_sizes, int n_in,
                              void* d_out, int out_size, void* d_ws, size_t ws_size,
                              hipStream_t stream) {
    const float* X    = (const float*)d_in[0];   // [B,4]
    const float* tlut = (const float*)d_in[1];   // [256,4]
    const int B = in_sizes[0] / 4;

    float* outX = (float*)d_out;          // first B*4 floats: hatX
    float* outS = outX + (size_t)B * 4;   // next B floats: state (as float)

    float* csq = (float*)d_ws;            // 256 floats of scratch

    vq_csq_kernel<<<1, 256, 0, stream>>>(tlut, csq);

    const int threads = B / PPT;          // 262144 for B=1M
    const int block = 256;
    const int grid = (threads + block - 1) / block;
    vq_argmin_kernel<<<grid, block, 0, stream>>>(X, tlut, csq, outX, outS, B);
}